// Round 7
// baseline (201.581 us; speedup 1.0000x reference)
//
#include <hip/hip_runtime.h>
#include <stdint.h>
#include <stddef.h>

// SIR scan: B=16384 batches, T=2048 steps, F=2 (beta,gamma), fp32.
// Round 7: pure-TLP design. 2048 blocks x 1 wave (8 batches each) ->
// 8 independent self-staging waves per CU spread across all 4 SIMDs,
// ZERO inter-wave sync (no barriers, no flags -> no convoy effect).
// Each DMA instruction now covers ONE row's 1 KB contiguous slice
// (single-segment coalescing, 2x DRAM granule vs rounds 1-6).
// Tests: per-SIMD stream cap (R6's null may have been SIMD collision)
// + DRAM granularity, in one experiment.

#define T_STEPS 2048
#define C_STEPS 128                  // timesteps per chunk
#define NCHUNK  (T_STEPS / C_STEPS)  // 16
#define BPB     8                    // batches per block (= per wave)
#define GRAN    (C_STEPS / 2)        // 64 16B-granules per row per chunk
#define IPC     8                    // DMA instrs per 8 KB chunk (1 per row)

#define INV_POP 1e-6f

// Stage chunk c: instruction j loads row j's full 1 KB slice.
// Lane l fetches global granule (l ^ j) -> LDS slot l of row j, i.e.
// LDS slot q holds global granule q^(j&7). Swizzle rides the GLOBAL
// address (rule #21); LDS dest linear per instruction.
__device__ __forceinline__ void stage_chunk(const float* __restrict__ in,
                                            float4* lds, int b0, int c, int lane)
{
#pragma unroll
    for (int j = 0; j < IPC; ++j) {
        const int p = lane ^ j;                 // j<8 so j&7==j
        const float* g = in
            + (size_t)(b0 + j) * (T_STEPS * 2)
            + (size_t)c * (C_STEPS * 2)
            + (size_t)(p * 4);
        float4* l = lds + j * 64;               // 1 KB per instruction, uniform
        __builtin_amdgcn_global_load_lds(
            (__attribute__((address_space(1))) void*)g,
            (__attribute__((address_space(3))) void*)l,
            16, 0, 0);
    }
}

// Consume one chunk: lane's row r = tid&7 (8-fold broadcast duplication,
// free). Read slot p^(r&7): 8 row-groups hit 8 distinct granule classes
// -> all 32 banks exactly once per phase, conflict-free.
__device__ __forceinline__ void compute_chunk(const float4* lds, int r,
                                              float& S, float& I, float& R)
{
    const int swz = r & 7;
    const float4* row = lds + r * GRAN;
#pragma unroll
    for (int p = 0; p < GRAN; ++p) {
        const float4 v = row[p ^ swz];   // steps 2p (v.x,v.y), 2p+1 (v.z,v.w)

        float ni = S * I * (v.x * INV_POP);
        float nr = v.y * I;
        S = S - ni;
        I = I + ni - nr;
        R = R + nr;

        ni = S * I * (v.z * INV_POP);
        nr = v.w * I;
        S = S - ni;
        I = I + ni - nr;
        R = R + nr;
    }
}

#define WAIT8() asm volatile("s_waitcnt vmcnt(8)" ::: "memory")
#define WAIT0() asm volatile("s_waitcnt vmcnt(0)" ::: "memory")

__global__ __launch_bounds__(64)
void sir_scan_kernel(const float* __restrict__ in, const float* __restrict__ init,
                     float* __restrict__ out, int half)
{
    __shared__ float4 bufA[BPB * GRAN];   // 8 KB
    __shared__ float4 bufB[BPB * GRAN];   // 8 KB  -> 16 KB/block, 8 blocks/CU

    const int tid = threadIdx.x;          // 0..63
    const int b0  = blockIdx.x * BPB;
    const int r   = tid & 7;              // row within block (8x duplicated)
    const int gb  = b0 + r;

    float S = init[gb * 3 + 0];
    float I = init[gb * 3 + 1];
    float R = init[gb * 3 + 2];

    // prologue: 2 chunks in flight (16 DMA instrs)
    stage_chunk(in, bufA, b0, 0, tid);
    stage_chunk(in, bufB, b0, 1, tid);

    // steady state: WAIT8 -> oldest chunk's 8 instrs retired (in-order
    // vmcnt), other buffer's 8 still in flight. Even if the compiler
    // inserts extra drains (R1/R2 failure mode), the other 7 waves on
    // this CU keep the memory system fed -- no sync between waves.
#pragma unroll 1
    for (int c = 0; c < NCHUNK - 2; c += 2) {
        WAIT8();
        compute_chunk(bufA, r, S, I, R);
        stage_chunk(in, bufA, b0, c + 2, tid);
        WAIT8();
        compute_chunk(bufB, r, S, I, R);
        stage_chunk(in, bufB, b0, c + 3, tid);
    }
    // chunks 14 (bufA), 15 (bufB)
    WAIT8();
    compute_chunk(bufA, r, S, I, R);
    WAIT0();
    compute_chunk(bufB, r, S, I, R);

    if (tid < 8) {
        out[gb * 3 + 0] = S;
        out[gb * 3 + 1] = I;
        out[gb * 3 + 2] = R;
        out[half + gb * 3 + 0] = S;
        out[half + gb * 3 + 1] = I;
        out[half + gb * 3 + 2] = R;
    }
}

extern "C" void kernel_launch(void* const* d_in, const int* in_sizes, int n_in,
                              void* d_out, int out_size, void* d_ws, size_t ws_size,
                              hipStream_t stream) {
    (void)in_sizes; (void)n_in; (void)d_ws; (void)ws_size;
    const float* in   = (const float*)d_in[0];   // (B, T, 2) fp32
    const float* init = (const float*)d_in[1];   // (B, 3)    fp32
    float* out        = (float*)d_out;           // 2 x (B, 3) fp32, concatenated
    const int half = out_size / 2;

    dim3 grid(16384 / BPB);   // 2048 blocks -> 8 waves/CU, 2 per SIMD
    dim3 block(64);           // 1 wave, fully self-contained
    sir_scan_kernel<<<grid, block, 0, stream>>>(in, init, out, half);
}

// Round 8
// 115.573 us; speedup vs baseline: 1.7442x; 1.7442x over previous
//
#include <hip/hip_runtime.h>
#include <stdint.h>
#include <stddef.h>

// SIR scan: B=16384 batches, T=2048 steps, F=2 (beta,gamma), fp32.
// Round 8: NO LDS, NO DMA, NO barriers. Each lane streams its own row
// directly to registers (global_load_dwordx4), relying on L1 to merge
// the 64-line-per-instruction pattern (each lane's 8 consecutive loads
// hit one 128B line; working set 3 groups x 64 lines = 24 KB < 32 KB L1).
// 3-deep register pipeline with NAMED groups (static indexing, rule #20)
// -- isolates whether the ~7.5 B/cyc/CU cap of R1/R3/R6 is specific to
// the global_load_lds path or a per-CU VMEM ceiling.

#define T_STEPS 2048
#define FPR     (T_STEPS * 2)        // floats per row = 4096
#define NGROUP  128                  // 128 groups x 8 float4 (32 floats)
#define INV_POP 1e-6f

__device__ __forceinline__ void load_group(const float4* __restrict__ row,
                                           int idx, float4* g)
{
    const float4* p = row + (size_t)idx * 8;
#pragma unroll
    for (int j = 0; j < 8; ++j) g[j] = p[j];   // j is compile-time constant
}

__device__ __forceinline__ void compute_group(const float4* g,
                                              float& S, float& I, float& R)
{
#pragma unroll
    for (int j = 0; j < 8; ++j) {              // 16 timesteps per group
        const float4 v = g[j];

        float ni = S * I * (v.x * INV_POP);
        float nr = v.y * I;
        S = S - ni;
        I = I + ni - nr;
        R = R + nr;

        ni = S * I * (v.z * INV_POP);
        nr = v.w * I;
        S = S - ni;
        I = I + ni - nr;
        R = R + nr;
    }
}

__global__ __launch_bounds__(64)
void sir_scan_kernel(const float* __restrict__ in, const float* __restrict__ init,
                     float* __restrict__ out, int half)
{
    const int tid = threadIdx.x;               // 0..63
    const int gb  = blockIdx.x * 64 + tid;     // this lane's batch
    const float4* row = (const float4*)(in + (size_t)gb * FPR);

    float S = init[gb * 3 + 0];
    float I = init[gb * 3 + 1];
    float R = init[gb * 3 + 2];

    // 3 named in-flight groups: 96 data VGPRs, ~2190 cyc latency coverage.
    float4 gA[8], gB[8], gC[8];
    load_group(row, 0, gA);
    load_group(row, 1, gB);
    load_group(row, 2, gC);

    // Iters k = 0,3,...,123 (42 iters): compute groups k..k+2, prefetch
    // k+3..k+5 (clamped: last iter re-loads 127, harmless). First use of
    // each group makes the compiler emit a counted vmcnt (16 younger
    // loads outstanding) -- precise register deps, no LDS conservatism.
#pragma unroll 1
    for (int k = 0; k < NGROUP - 2; k += 3) {
        compute_group(gA, S, I, R);
        { const int n = k + 3; load_group(row, n < NGROUP ? n : NGROUP - 1, gA); }
        compute_group(gB, S, I, R);
        { const int n = k + 4; load_group(row, n < NGROUP ? n : NGROUP - 1, gB); }
        compute_group(gC, S, I, R);
        { const int n = k + 5; load_group(row, n < NGROUP ? n : NGROUP - 1, gC); }
    }
    // After the loop: gA = group 126, gB = group 127 (gC = clamped dup).
    compute_group(gA, S, I, R);
    compute_group(gB, S, I, R);

    // reference returns (final_state, final_state): write both halves
    out[gb * 3 + 0] = S;
    out[gb * 3 + 1] = I;
    out[gb * 3 + 2] = R;
    out[half + gb * 3 + 0] = S;
    out[half + gb * 3 + 1] = I;
    out[half + gb * 3 + 2] = R;
}

extern "C" void kernel_launch(void* const* d_in, const int* in_sizes, int n_in,
                              void* d_out, int out_size, void* d_ws, size_t ws_size,
                              hipStream_t stream) {
    (void)in_sizes; (void)n_in; (void)d_ws; (void)ws_size;
    const float* in   = (const float*)d_in[0];   // (B, T, 2) fp32
    const float* init = (const float*)d_in[1];   // (B, 3)    fp32
    float* out        = (float*)d_out;           // 2 x (B, 3) fp32, concatenated
    const int half = out_size / 2;

    dim3 grid(16384 / 64);    // 256 blocks, 1 wave each, 1 per CU
    dim3 block(64);
    sir_scan_kernel<<<grid, block, 0, stream>>>(in, init, out, half);
}

// Round 9
// 58.512 us; speedup vs baseline: 3.4451x; 1.9752x over previous
//
#include <hip/hip_runtime.h>
#include <stdint.h>
#include <stddef.h>
#include <math.h>

// SIR scan: B=16384 batches, T=2048 steps, F=2 (beta,gamma), fp32.
// Round 9: R3 skeleton VERBATIM (best: 57.4us), ONLY the consumer math
// restructured:  S' = S*(1 - u*I),  I' = I*((1-g) + u*S),  u = beta/P.
// -> dependent chain 16 -> 8 cyc/step (2 FMAs), ~25% fewer VALU ops;
// R accumulated off-chain (rsum), R_final = R0 + rsum.
// Discriminates: (a) chip-level pattern ceiling (~4.7 TB/s for 16384
// strided streams) vs (b) consumer compute adding to the chunk period.

#define T_STEPS 2048
#define C_STEPS 64                   // timesteps per chunk
#define NCHUNK  (T_STEPS / C_STEPS)  // 32
#define BPB     64                   // batches per block
#define PAIRS   (C_STEPS / 2)        // 32 float4 slots per batch per chunk
#define IPC     32                   // global_load_lds instrs per 32 KB chunk

#define INV_POP 1e-6f

// Stage chunk c of this block's 64 batches into lds (linear dest,
// swizzle carried by the per-lane GLOBAL address -- rule #21).
// Instruction j covers batches {2j, 2j+1}: lane l -> batch 2j + (l>>5),
// slot q = l&31, global pair p = q ^ (batch&15).
__device__ __forceinline__ void stage_chunk(const float* __restrict__ in,
                                            float4* lds, int b0, int c, int lane)
{
    const int hi = lane >> 5;   // 0 or 1
    const int q  = lane & 31;
#pragma unroll
    for (int j = 0; j < IPC; ++j) {
        const int bi = 2 * j + hi;              // batch within block
        const int p  = q ^ (bi & 15);           // swizzled global pair index
        const float* g = in
            + (size_t)(b0 + bi) * (T_STEPS * 2)
            + (size_t)c * (C_STEPS * 2)
            + (size_t)(p * 4);
        float4* l = lds + j * 64;               // 1 KB per instruction, uniform
        __builtin_amdgcn_global_load_lds(
            (__attribute__((address_space(1))) void*)g,
            (__attribute__((address_space(3))) void*)l,
            16, 0, 0);
    }
}

// Consume one chunk: 32 ds_read_b128 per lane (XOR swizzle), 64 steps.
// Restructured: per step, chain = t(4cy) -> fma(4cy); all else parallel.
__device__ __forceinline__ void compute_chunk(const float4* lds, int tid,
                                              float& S, float& I, float& rsum)
{
    const int swz = tid & 15;
    const float4* row = lds + tid * PAIRS;
#pragma unroll
    for (int p = 0; p < PAIRS; ++p) {
        const float4 v = row[p ^ swz];   // steps 2p (v.x,v.y), 2p+1 (v.z,v.w)

        // step 2p: beta=v.x, gamma=v.y
        float u  = v.x * INV_POP;
        float t1 = u * S;                 // on S-chain
        float t2 = u * I;                 // on I-chain
        float w  = fmaf(-v.y, I, I);      // I*(1-g), off both chains
        rsum     = fmaf(v.y, I, rsum);    // R accumulation, off-chain
        I = fmaf(I, t1, w);               // I' = I*u*S + I*(1-g)
        S = fmaf(-t2, S, S);              // S' = S - u*I*S

        // step 2p+1: beta=v.z, gamma=v.w
        u  = v.z * INV_POP;
        t1 = u * S;
        t2 = u * I;
        w  = fmaf(-v.w, I, I);
        rsum = fmaf(v.w, I, rsum);
        I = fmaf(I, t1, w);
        S = fmaf(-t2, S, S);
    }
}

#define BAR()    asm volatile("s_barrier" ::: "memory")
#define WAIT32() asm volatile("s_waitcnt vmcnt(32)" ::: "memory")
#define WAIT0()  asm volatile("s_waitcnt vmcnt(0)"  ::: "memory")

__global__ __launch_bounds__(128)
void sir_scan_kernel(const float* __restrict__ in, const float* __restrict__ init,
                     float* __restrict__ out, int half)
{
    // 4 x 32 KB = 128 KB (1 block/CU), statically distinct objects
    __shared__ float4 buf0[BPB * PAIRS];
    __shared__ float4 buf1[BPB * PAIRS];
    __shared__ float4 buf2[BPB * PAIRS];
    __shared__ float4 buf3[BPB * PAIRS];

    const int tid = threadIdx.x;
    const int b0  = blockIdx.x * BPB;

    if (tid < 64) {
        // ---------------- consumer wave: zero outstanding VMEM in the loop
        const int gb = b0 + tid;
        float S  = init[gb * 3 + 0];
        float I  = init[gb * 3 + 1];
        float R0 = init[gb * 3 + 2];
        float rsum = 0.0f;

        // BAR #c <=> "chunk c has landed" (producer waits vmcnt first)
#pragma unroll 1
        for (int c = 0; c < NCHUNK; c += 4) {
            BAR(); compute_chunk(buf0, tid, S, I, rsum);
            BAR(); compute_chunk(buf1, tid, S, I, rsum);
            BAR(); compute_chunk(buf2, tid, S, I, rsum);
            BAR(); compute_chunk(buf3, tid, S, I, rsum);
        }

        const float R = R0 + rsum;
        out[gb * 3 + 0] = S;
        out[gb * 3 + 1] = I;
        out[gb * 3 + 2] = R;
        out[half + gb * 3 + 0] = S;
        out[half + gb * 3 + 1] = I;
        out[half + gb * 3 + 2] = R;
    } else {
        // ---------------- producer wave: all staging + counted waits here
        const int lane = tid - 64;

        stage_chunk(in, buf0, b0, 0, lane);
        stage_chunk(in, buf1, b0, 1, lane);

        // Invariant at each WAIT32: outstanding = chunks {c, c+1} (64
        // instrs); vmcnt(32) => chunk c fully landed, c+1 in flight.
        // After BAR #c we stage chunk c+2 into buf[(c+2)%4], which the
        // consumer finished two barriers ago (lockstep => WAR safe).
#pragma unroll 1
        for (int c = 0; c < NCHUNK - 4; c += 4) {
            WAIT32(); BAR(); stage_chunk(in, buf2, b0, c + 2, lane);
            WAIT32(); BAR(); stage_chunk(in, buf3, b0, c + 3, lane);
            WAIT32(); BAR(); stage_chunk(in, buf0, b0, c + 4, lane);
            WAIT32(); BAR(); stage_chunk(in, buf1, b0, c + 5, lane);
        }
        // chunks 28..31: stage only 30, 31
        WAIT32(); BAR(); stage_chunk(in, buf2, b0, NCHUNK - 2, lane);
        WAIT32(); BAR(); stage_chunk(in, buf3, b0, NCHUNK - 1, lane);
        WAIT32(); BAR();   // chunk 30 landed (outstanding {30,31})
        WAIT0();  BAR();   // chunk 31 landed
    }
}

extern "C" void kernel_launch(void* const* d_in, const int* in_sizes, int n_in,
                              void* d_out, int out_size, void* d_ws, size_t ws_size,
                              hipStream_t stream) {
    (void)in_sizes; (void)n_in; (void)d_ws; (void)ws_size;
    const float* in   = (const float*)d_in[0];   // (B, T, 2) fp32
    const float* init = (const float*)d_in[1];   // (B, 3)    fp32
    float* out        = (float*)d_out;           // 2 x (B, 3) fp32, concatenated
    const int half = out_size / 2;

    dim3 grid(16384 / BPB);   // 256 blocks, 1 per CU
    dim3 block(128);          // wave 0 = consumer, wave 1 = producer
    sir_scan_kernel<<<grid, block, 0, stream>>>(in, init, out, half);
}